// Round 1
// baseline (2165.411 us; speedup 1.0000x reference)
//
#include <hip/hip_runtime.h>
#include <hip/hip_bf16.h>
#include <cstdint>
#include <cstddef>

#define EPSBN 0.001f

// problem dims
#define NN 16
#define CCH 512
#define HHH 56
#define WW 56
#define GG 8
#define DD 1024
#define BB (NN*WW)          /* 896  */
#define NCOLC (BB*HHH)      /* 50176 */
#define KKC 512

__device__ __forceinline__ float bfbits2f(unsigned v){ return __uint_as_float(v << 16); }
__device__ __forceinline__ unsigned short f2bfbits(float f){
    __hip_bfloat16 h = __float2bfloat16(f);
    return *reinterpret_cast<unsigned short*>(&h);
}
__device__ __forceinline__ float toF(float x){ return x; }
__device__ __forceinline__ float toF(__hip_bfloat16 x){ return __bfloat162float(x); }
__device__ __forceinline__ void stT(float* p, float v){ *p = v; }
__device__ __forceinline__ void stT(__hip_bfloat16* p, float v){ *p = __float2bfloat16(v); }

// ---------------------------------------------------------------------------
// Kernel 0: gather rel_emb -> emb[128][56][56]
//   rows  0..31  : q_emb[c][i][j]   = rel[c][i-j+55]
//   rows 32..63  : keT[c][i][j]     = k_emb[c][j][i] = rel[32+c][j-i+55]  (pre-transposed!)
//   rows 64..127 : v_emb[c][i][j]   = rel[64+c][i-j+55]
// ---------------------------------------------------------------------------
__global__ void emb_gather_k(const float* __restrict__ rel, float* __restrict__ emb){
    int idx = blockIdx.x*256 + threadIdx.x;
    if (idx >= 128*3136) return;
    int c = idx / 3136, r = idx - c*3136;
    int i = r / 56, j = r - i*56;
    int off = (c >= 32 && c < 64) ? (j - i + 55) : (i - j + 55);
    emb[idx] = rel[c*111 + off];
}

// ---------------------------------------------------------------------------
// Kernel 1: transpose x[N][C][H][W] -> xt[(n*3136 + w*56 + h)][c]   (B^T layout)
// ---------------------------------------------------------------------------
template<typename T>
__global__ __launch_bounds__(256) void xpose_k(const float* __restrict__ x, T* __restrict__ xt){
    __shared__ float tile[32][33];
    int bx = blockIdx.x;
    int wb = bx >> 4, cb = bx & 15;      // wb: 0..1 (w tile), cb: 0..15 (c tile)
    int h = blockIdx.y, n = blockIdx.z;
    int tx = threadIdx.x & 31, ty = threadIdx.x >> 5;
    int w = wb*32 + tx;
    if (w < 56){
        #pragma unroll
        for (int rr=0; rr<4; rr++){
            int cl = ty + 8*rr;
            tile[cl][tx] = x[(((size_t)n*CCH + cb*32 + cl)*HHH + h)*WW + w];
        }
    }
    __syncthreads();
    #pragma unroll
    for (int rr=0; rr<4; rr++){
        int wi = ty + 8*rr;
        int w2 = wb*32 + wi;
        if (w2 < 56){
            size_t col = (size_t)n*3136 + (size_t)w2*56 + h;
            stT(&xt[col*KKC + cb*32 + tx], tile[tx][wi]);
        }
    }
}

// ---------------------------------------------------------------------------
// Kernel 2: qkv[d][col] = BN( sum_k w[d][k] * xt[col][k] )
//   M=1024, N=50176, K=512.  BM=BN=64, BK=32, 4x4 micro-tile, 256 threads.
//   grid = (16 bm, 784 bn): consecutive blocks share the B-panel -> B read once.
// ---------------------------------------------------------------------------
template<typename T>
__global__ __launch_bounds__(256) void qkvgemm_k(
    const float* __restrict__ A, const T* __restrict__ Bt, T* __restrict__ Co,
    const float* __restrict__ gg, const float* __restrict__ bb,
    const float* __restrict__ mm, const float* __restrict__ vv)
{
    __shared__ float As[32][68];
    __shared__ float Bs[32][68];
    const int bm = blockIdx.x, bn = blockIdx.y;
    const int t  = threadIdx.x;
    const int tm = t >> 4, tn = t & 15;
    const int m0 = bm*64;
    const size_t n0 = (size_t)bn*64;

    float acc[4][4];
    #pragma unroll
    for (int r=0;r<4;r++)
        #pragma unroll
        for (int c=0;c<4;c++) acc[r][c] = 0.f;

    const int srow = t >> 2;        // 0..63
    const int kb   = (t & 3) * 8;   // k sub-range within the 32-wide chunk

    for (int kk = 0; kk < KKC; kk += 32){
        {   // stage A (always f32), transposed into As[k][m]
            const float* src = &A[(size_t)(m0+srow)*KKC + kk + kb];
            float4 f1 = *reinterpret_cast<const float4*>(src);
            float4 f2 = *reinterpret_cast<const float4*>(src+4);
            As[kb+0][srow]=f1.x; As[kb+1][srow]=f1.y; As[kb+2][srow]=f1.z; As[kb+3][srow]=f1.w;
            As[kb+4][srow]=f2.x; As[kb+5][srow]=f2.y; As[kb+6][srow]=f2.z; As[kb+7][srow]=f2.w;
        }
        if constexpr (sizeof(T) == 4) {
            const float* src = reinterpret_cast<const float*>(Bt) + (n0+srow)*KKC + kk + kb;
            float4 f1 = *reinterpret_cast<const float4*>(src);
            float4 f2 = *reinterpret_cast<const float4*>(src+4);
            Bs[kb+0][srow]=f1.x; Bs[kb+1][srow]=f1.y; Bs[kb+2][srow]=f1.z; Bs[kb+3][srow]=f1.w;
            Bs[kb+4][srow]=f2.x; Bs[kb+5][srow]=f2.y; Bs[kb+6][srow]=f2.z; Bs[kb+7][srow]=f2.w;
        } else {
            const unsigned short* src = reinterpret_cast<const unsigned short*>(Bt) + (n0+srow)*KKC + kk + kb;
            uint4 u = *reinterpret_cast<const uint4*>(src);
            Bs[kb+0][srow]=bfbits2f(u.x & 0xffffu); Bs[kb+1][srow]=bfbits2f(u.x >> 16);
            Bs[kb+2][srow]=bfbits2f(u.y & 0xffffu); Bs[kb+3][srow]=bfbits2f(u.y >> 16);
            Bs[kb+4][srow]=bfbits2f(u.z & 0xffffu); Bs[kb+5][srow]=bfbits2f(u.z >> 16);
            Bs[kb+6][srow]=bfbits2f(u.w & 0xffffu); Bs[kb+7][srow]=bfbits2f(u.w >> 16);
        }
        __syncthreads();
        #pragma unroll
        for (int k=0;k<32;k++){
            float4 a4 = *reinterpret_cast<const float4*>(&As[k][tm*4]);
            float4 b4 = *reinterpret_cast<const float4*>(&Bs[k][tn*4]);
            acc[0][0]=fmaf(a4.x,b4.x,acc[0][0]); acc[0][1]=fmaf(a4.x,b4.y,acc[0][1]);
            acc[0][2]=fmaf(a4.x,b4.z,acc[0][2]); acc[0][3]=fmaf(a4.x,b4.w,acc[0][3]);
            acc[1][0]=fmaf(a4.y,b4.x,acc[1][0]); acc[1][1]=fmaf(a4.y,b4.y,acc[1][1]);
            acc[1][2]=fmaf(a4.y,b4.z,acc[1][2]); acc[1][3]=fmaf(a4.y,b4.w,acc[1][3]);
            acc[2][0]=fmaf(a4.z,b4.x,acc[2][0]); acc[2][1]=fmaf(a4.z,b4.y,acc[2][1]);
            acc[2][2]=fmaf(a4.z,b4.z,acc[2][2]); acc[2][3]=fmaf(a4.z,b4.w,acc[2][3]);
            acc[3][0]=fmaf(a4.w,b4.x,acc[3][0]); acc[3][1]=fmaf(a4.w,b4.y,acc[3][1]);
            acc[3][2]=fmaf(a4.w,b4.z,acc[3][2]); acc[3][3]=fmaf(a4.w,b4.w,acc[3][3]);
        }
        __syncthreads();
    }
    #pragma unroll
    for (int r=0;r<4;r++){
        const int d = m0 + tm*4 + r;
        const float s  = gg[d]*rsqrtf(vv[d]+EPSBN);
        const float sh = bb[d] - mm[d]*s;
        const size_t base = (size_t)d*NCOLC + n0 + tn*4;
        float o0 = fmaf(acc[r][0],s,sh), o1 = fmaf(acc[r][1],s,sh);
        float o2 = fmaf(acc[r][2],s,sh), o3 = fmaf(acc[r][3],s,sh);
        if constexpr (sizeof(T) == 4){
            *reinterpret_cast<float4*>(reinterpret_cast<float*>(Co)+base) = make_float4(o0,o1,o2,o3);
        } else {
            ushort4 o; o.x=f2bfbits(o0); o.y=f2bfbits(o1); o.z=f2bfbits(o2); o.w=f2bfbits(o3);
            *reinterpret_cast<ushort4*>(reinterpret_cast<unsigned short*>(Co)+base) = o;
        }
    }
}

// ---------------------------------------------------------------------------
// Kernel 3: fused attention per (b, g).
//   sim = BN(qk) + BN(qr) + BN(kr^T); softmax; y = BN(attn@v + attn*v_emb)
// ---------------------------------------------------------------------------
template<typename T>
__global__ __launch_bounds__(256) void attn_k(
    const T* __restrict__ qkv, const float* __restrict__ emb,
    const float* __restrict__ sgam, const float* __restrict__ sbet,
    const float* __restrict__ smea, const float* __restrict__ svar,
    const float* __restrict__ ogam, const float* __restrict__ obet,
    const float* __restrict__ omea, const float* __restrict__ ovar,
    float* __restrict__ out)
{
    __shared__ float qs[32][56];
    __shared__ float ks[32][56];
    __shared__ float vs[64][56];
    __shared__ float ats[56][57];

    const int b = blockIdx.x;          // 0..895  (= n*56 + w)
    const int g = blockIdx.y;          // 0..7
    const int n = b / 56, w = b - n*56;
    const int t = threadIdx.x;
    const size_t colbase = (size_t)b*56;
    const size_t rowQ = (size_t)(g*128)*NCOLC;

    for (int idx = t; idx < 32*56; idx += 256){
        int c = idx/56, h = idx - c*56;
        qs[c][h] = toF(qkv[rowQ + (size_t)c      *NCOLC + colbase + h]);
        ks[c][h] = toF(qkv[rowQ + (size_t)(32+c) *NCOLC + colbase + h]);
    }
    for (int idx = t; idx < 64*56; idx += 256){
        int c = idx/56, h = idx - c*56;
        vs[c][h] = toF(qkv[rowQ + (size_t)(64+c) *NCOLC + colbase + h]);
    }
    __syncthreads();

    const float s0 = sgam[g]    * rsqrtf(svar[g]    + EPSBN);
    const float h0 = sbet[g]    - smea[g]*s0;
    const float s1 = sgam[8+g]  * rsqrtf(svar[8+g]  + EPSBN);
    const float h1 = sbet[8+g]  - smea[8+g]*s1;
    const float s2 = sgam[16+g] * rsqrtf(svar[16+g] + EPSBN);
    const float h2 = sbet[16+g] - smea[16+g]*s2;

    const float* qe  = emb;             // [32][3136]
    const float* keT = emb + 32*3136;   // pre-transposed k_emb
    const float* ve  = emb + 64*3136;   // [64][3136]

    for (int idx = t; idx < 3136; idx += 256){
        int i = idx/56, j = idx - i*56;
        float qk = 0.f, qr = 0.f, kr = 0.f;
        #pragma unroll 8
        for (int c=0;c<32;c++){
            float qv = qs[c][i], kv = ks[c][j];
            qk = fmaf(qv, kv, qk);
            qr = fmaf(qv, qe [c*3136 + idx], qr);
            kr = fmaf(kv, keT[c*3136 + idx], kr);
        }
        ats[i][j] = fmaf(qk,s0,h0) + fmaf(qr,s1,h1) + fmaf(kr,s2,h2);
    }
    __syncthreads();

    // softmax: one wave per row, lanes = columns
    const int wv = t >> 6, lane = t & 63;
    for (int i = wv; i < 56; i += 4){
        float val = (lane < 56) ? ats[i][lane] : -1e30f;
        float mx = val;
        #pragma unroll
        for (int o=32;o;o>>=1) mx = fmaxf(mx, __shfl_xor(mx, o));
        float e = (lane < 56) ? __expf(val - mx) : 0.f;
        float sm = e;
        #pragma unroll
        for (int o=32;o;o>>=1) sm += __shfl_xor(sm, o);
        if (lane < 56) ats[i][lane] = e / sm;
    }
    __syncthreads();

    for (int idx = t; idx < 64*56; idx += 256){
        int c = idx/56, i = idx - c*56;
        int oc = g*64 + c;
        float s  = ogam[oc]*rsqrtf(ovar[oc]+EPSBN);
        float hh = obet[oc] - omea[oc]*s;
        const float* vr = ve + c*3136 + i*56;
        float sv = 0.f, sve = 0.f;
        #pragma unroll 8
        for (int j=0;j<56;j++){
            float a = ats[i][j];
            sv  = fmaf(a, vs[c][j], sv);
            sve = fmaf(a, vr[j],    sve);
        }
        out[(((size_t)n*CCH + oc)*HHH + i)*WW + w] = (sv+sve)*s + hh;
    }
}

// ---------------------------------------------------------------------------
extern "C" void kernel_launch(void* const* d_in, const int* in_sizes, int n_in,
                              void* d_out, int out_size, void* d_ws, size_t ws_size,
                              hipStream_t stream)
{
    const float* x     = (const float*)d_in[0];
    const float* w_qkv = (const float*)d_in[1];
    const float* qg    = (const float*)d_in[2];
    const float* qb    = (const float*)d_in[3];
    const float* qm    = (const float*)d_in[4];
    const float* qvv   = (const float*)d_in[5];
    const float* rel   = (const float*)d_in[6];
    const float* sg    = (const float*)d_in[7];
    const float* sb    = (const float*)d_in[8];
    const float* sm    = (const float*)d_in[9];
    const float* sv    = (const float*)d_in[10];
    const float* og    = (const float*)d_in[11];
    const float* ob    = (const float*)d_in[12];
    const float* om    = (const float*)d_in[13];
    const float* ov    = (const float*)d_in[14];
    float* out = (float*)d_out;

    char*  ws   = (char*)d_ws;
    float* emb  = (float*)ws;
    const size_t embB = (size_t)128*3136*4;       // 1,605,632 B
    const size_t xtE  = (size_t)NCOLC*KKC;        // 25,690,112 elems
    const size_t qkvE = (size_t)DD*NCOLC;         // 51,380,224 elems

    emb_gather_k<<<dim3(1568), dim3(256), 0, stream>>>(rel, emb);

    const size_t needF = embB + (xtE + qkvE)*4;   // ~296 MiB
    const size_t needH = embB + (xtE + qkvE)*2;   // ~149 MiB

    if (ws_size >= needF) {
        float* xt  = (float*)(ws + embB);
        float* qkv = xt + xtE;
        xpose_k<float><<<dim3(32,56,16), dim3(256), 0, stream>>>(x, xt);
        qkvgemm_k<float><<<dim3(16,784), dim3(256), 0, stream>>>(w_qkv, xt, qkv, qg,qb,qm,qvv);
        attn_k<float><<<dim3(896,8), dim3(256), 0, stream>>>(qkv, emb, sg,sb,sm,sv, og,ob,om,ov, out);
    } else if (ws_size >= needH) {
        __hip_bfloat16* xt  = (__hip_bfloat16*)(ws + embB);
        __hip_bfloat16* qkv = xt + xtE;
        xpose_k<__hip_bfloat16><<<dim3(32,56,16), dim3(256), 0, stream>>>(x, xt);
        qkvgemm_k<__hip_bfloat16><<<dim3(16,784), dim3(256), 0, stream>>>(w_qkv, xt, qkv, qg,qb,qm,qvv);
        attn_k<__hip_bfloat16><<<dim3(896,8), dim3(256), 0, stream>>>(qkv, emb, sg,sb,sm,sv, og,ob,om,ov, out);
    }
    (void)in_sizes; (void)n_in; (void)out_size;
}

// Round 3
// 992.920 us; speedup vs baseline: 2.1809x; 2.1809x over previous
//
#include <hip/hip_runtime.h>
#include <hip/hip_bf16.h>
#include <cstdint>
#include <cstddef>

#define EPSBN 0.001f
#define NCOL 50176
#define KKC 512

typedef _Float16 f16x8 __attribute__((ext_vector_type(8)));
typedef _Float16 f16x4 __attribute__((ext_vector_type(4)));
typedef float f32x4 __attribute__((ext_vector_type(4)));

__device__ __forceinline__ float bf2f(unsigned u){ return __uint_as_float(u << 16); }

#define GLOAD_LDS16(g, l) __builtin_amdgcn_global_load_lds( \
    (const __attribute__((address_space(1))) void*)(g),     \
    (__attribute__((address_space(3))) void*)(l), 16, 0, 0)

// ---------------------------------------------------------------------------
// w_qkv fp32 [1024][512] -> (hi, lo*256) f16 pairs, rows PERMUTED:
//   q(g,c)->g*32+c ; k(g,c)->256+g*32+c ; v(g,c)->512+g*64+c
// ---------------------------------------------------------------------------
__global__ void convw_k(const float* __restrict__ w,
                        _Float16* __restrict__ wh, _Float16* __restrict__ wl){
    int idx = blockIdx.x*256 + threadIdx.x;       // 131072 float4 groups
    int d = idx >> 7, kq = (idx & 127) * 4;
    int g = d >> 7, loc = d & 127;
    int nd = (loc < 32) ? (g*32 + loc)
           : (loc < 64) ? (256 + g*32 + loc - 32)
                        : (512 + g*64 + loc - 64);
    float4 f = ((const float4*)w)[idx];
    f16x4 h, l;
    h[0]=(_Float16)f.x; l[0]=(_Float16)((f.x-(float)h[0])*256.f);
    h[1]=(_Float16)f.y; l[1]=(_Float16)((f.y-(float)h[1])*256.f);
    h[2]=(_Float16)f.z; l[2]=(_Float16)((f.z-(float)h[2])*256.f);
    h[3]=(_Float16)f.w; l[3]=(_Float16)((f.w-(float)h[3])*256.f);
    *(f16x4*)(wh + (size_t)nd*KKC + kq) = h;
    *(f16x4*)(wl + (size_t)nd*KKC + kq) = l;
}

// ---------------------------------------------------------------------------
// rel_emb -> emb[128][3136] fp32 (rows 32..63 pre-transposed for kr)
// ---------------------------------------------------------------------------
__global__ void embg_k(const float* __restrict__ rel, float* __restrict__ emb){
    int idx = blockIdx.x*256 + threadIdx.x;
    if (idx >= 128*3136) return;
    int c = idx / 3136, r = idx - c*3136;
    int i = r / 56, j = r - i*56;
    int off = (c >= 32 && c < 64) ? (j - i + 55) : (i - j + 55);
    emb[idx] = rel[c*111 + off];
}

// ---------------------------------------------------------------------------
// transpose x[N][C][H][W] -> xt_h/xt_l[(n*3136+w*56+h)][c]  (hi, lo*256) f16
// ---------------------------------------------------------------------------
__global__ __launch_bounds__(256) void xpose_k(const float* __restrict__ x,
                                               _Float16* __restrict__ xth,
                                               _Float16* __restrict__ xtl){
    __shared__ float tile[32][33];
    int bx = blockIdx.x;
    int wb = bx >> 4, cb = bx & 15;
    int h = blockIdx.y, n = blockIdx.z;
    int tx = threadIdx.x & 31, ty = threadIdx.x >> 5;
    int w = wb*32 + tx;
    if (w < 56){
        #pragma unroll
        for (int rr=0; rr<4; rr++){
            int cl = ty + 8*rr;
            tile[cl][tx] = x[(((size_t)n*512 + cb*32 + cl)*56 + h)*56 + w];
        }
    }
    __syncthreads();
    #pragma unroll
    for (int rr=0; rr<4; rr++){
        int wi = ty + 8*rr;
        int w2 = wb*32 + wi;
        if (w2 < 56){
            size_t col = (size_t)n*3136 + (size_t)w2*56 + h;
            float v = tile[tx][wi];
            _Float16 hh = (_Float16)v;
            xth[col*KKC + cb*32 + tx] = hh;
            xtl[col*KKC + cb*32 + tx] = (_Float16)((v - (float)hh)*256.f);
        }
    }
}

// ---------------------------------------------------------------------------
// MFMA GEMM, 128x128 tile, BK=32, 2x2 waves, 4x4 frags.
// PREC: 3-pass split-f16 (fp32-accurate), fp32 out rows 0..511 (q,k).
// FAST: 1-pass f16, bf16 out rows 512..1023 (v).
// ---------------------------------------------------------------------------
template<bool PREC>
__global__ __launch_bounds__(256) void gemm_k(
    const _Float16* __restrict__ Wh, const _Float16* __restrict__ Wl,
    const _Float16* __restrict__ Xh, const _Float16* __restrict__ Xl,
    float* __restrict__ Cf, __hip_bfloat16* __restrict__ Cb,
    const float* __restrict__ gg, const float* __restrict__ bb,
    const float* __restrict__ mm, const float* __restrict__ vv)
{
    __shared__ _Float16 sm[PREC ? 16384 : 8192];
    _Float16* Ash = sm;
    _Float16* Bsh = sm + 4096;

    const int t = threadIdx.x;
    const int wvi = t >> 6, lane = t & 63;
    const int wr = wvi >> 1, wc = wvi & 1;
    const int d_base = PREC ? 0 : 512;
    const int m0 = blockIdx.x * 128;
    const size_t n0 = (size_t)blockIdx.y * 128;

    const int srow = wvi*32 + (lane >> 2);
    const int scol = (lane & 3) * 8;
    const _Float16* gAh = Wh + (size_t)(d_base + m0 + srow)*KKC + scol;
    const _Float16* gBh = Xh + (n0 + srow)*KKC + scol;
    _Float16* lAh = Ash + wvi*1024;
    _Float16* lBh = Bsh + wvi*1024;

    f32x4 acc1[4][4] = {};
    f32x4 acc2[PREC?4:1][PREC?4:1] = {};

    const int fr = lane & 15, k8 = (lane >> 4) * 8;

    for (int kk = 0; kk < KKC; kk += 32){
        GLOAD_LDS16(gAh + kk,          lAh);
        GLOAD_LDS16(gAh + kk + 16*KKC, lAh + 512);
        GLOAD_LDS16(gBh + kk,          lBh);
        GLOAD_LDS16(gBh + kk + 16*KKC, lBh + 512);
        if constexpr (PREC){
            const _Float16* gAl = Wl + (size_t)(m0 + srow)*KKC + scol;
            const _Float16* gBl = Xl + (n0 + srow)*KKC + scol;
            _Float16* lAl = sm + 8192  + wvi*1024;
            _Float16* lBl = sm + 12288 + wvi*1024;
            GLOAD_LDS16(gAl + kk,          lAl);
            GLOAD_LDS16(gAl + kk + 16*KKC, lAl + 512);
            GLOAD_LDS16(gBl + kk,          lBl);
            GLOAD_LDS16(gBl + kk + 16*KKC, lBl + 512);
        }
        asm volatile("s_waitcnt vmcnt(0)" ::: "memory");
        __syncthreads();

        f16x8 ah[4], bh[4];
        #pragma unroll
        for (int mi = 0; mi < 4; mi++)
            ah[mi] = *(const f16x8*)(Ash + (wr*64 + mi*16 + fr)*32 + k8);
        #pragma unroll
        for (int ni = 0; ni < 4; ni++)
            bh[ni] = *(const f16x8*)(Bsh + (wc*64 + ni*16 + fr)*32 + k8);
        #pragma unroll
        for (int mi = 0; mi < 4; mi++)
            #pragma unroll
            for (int ni = 0; ni < 4; ni++)
                acc1[mi][ni] = __builtin_amdgcn_mfma_f32_16x16x32_f16(ah[mi], bh[ni], acc1[mi][ni], 0,0,0);
        if constexpr (PREC){
            f16x8 al[4], bl[4];
            #pragma unroll
            for (int mi = 0; mi < 4; mi++)
                al[mi] = *(const f16x8*)(sm + 8192 + (wr*64 + mi*16 + fr)*32 + k8);
            #pragma unroll
            for (int ni = 0; ni < 4; ni++)
                bl[ni] = *(const f16x8*)(sm + 12288 + (wc*64 + ni*16 + fr)*32 + k8);
            #pragma unroll
            for (int mi = 0; mi < 4; mi++)
                #pragma unroll
                for (int ni = 0; ni < 4; ni++){
                    acc2[mi][ni] = __builtin_amdgcn_mfma_f32_16x16x32_f16(al[mi], bh[ni], acc2[mi][ni], 0,0,0);
                    acc2[mi][ni] = __builtin_amdgcn_mfma_f32_16x16x32_f16(ah[mi], bl[ni], acc2[mi][ni], 0,0,0);
                }
        }
        __syncthreads();
    }

    #pragma unroll
    for (int mi = 0; mi < 4; mi++){
        #pragma unroll
        for (int r = 0; r < 4; r++){
            const int lrow = m0 + wr*64 + mi*16 + (lane>>4)*4 + r;
            const int nd = d_base + lrow;
            int orig;
            if constexpr (PREC){
                orig = (nd < 256) ? ((nd>>5)*128 + (nd&31))
                                  : (((nd-256)>>5)*128 + 32 + ((nd-256)&31));
            } else {
                int u = nd - 512;
                orig = (u>>6)*128 + 64 + (u&63);
            }
            const float s  = gg[orig]*rsqrtf(vv[orig]+EPSBN);
            const float sh = bb[orig] - mm[orig]*s;
            #pragma unroll
            for (int ni = 0; ni < 4; ni++){
                const size_t col = n0 + wc*64 + ni*16 + (lane&15);
                if constexpr (PREC){
                    float val = acc1[mi][ni][r] + acc2[mi][ni][r]*(1.f/256.f);
                    Cf[(size_t)nd*NCOL + col] = fmaf(val, s, sh);
                } else {
                    Cb[(size_t)lrow*NCOL + col] = __float2bfloat16(fmaf(acc1[mi][ni][r], s, sh));
                }
            }
        }
    }
}

// ---------------------------------------------------------------------------
// Fused attention: block = (seg of 28 i-rows, b); all 8 heads per block.
// q/k/emb/weights fp32; v bf16. Phase1 scores+BN+softmax; Phase2 sv+sve+BN.
// ---------------------------------------------------------------------------
__global__ __launch_bounds__(512) void attn3_k(
    const float* __restrict__ QK, const __hip_bfloat16* __restrict__ V,
    const float* __restrict__ emb,
    const float* __restrict__ sgm, const float* __restrict__ sbt,
    const float* __restrict__ smn, const float* __restrict__ svr,
    const float* __restrict__ ogm, const float* __restrict__ obt,
    const float* __restrict__ omn, const float* __restrict__ ovr,
    __hip_bfloat16* __restrict__ y_ws)
{
    __shared__ __align__(16) float k_s[8][32][56];   // 57344 B (phase2: v_s overlay)
    __shared__ __align__(16) float q_s[8][32][28];   // 28672 B
    __shared__ __align__(16) float ats[8][28][58];   // 51968 B
    __hip_bfloat16 (*v_s)[64][56] = reinterpret_cast<__hip_bfloat16(*)[64][56]>(&k_s[0][0][0]);

    const int seg = blockIdx.x, b = blockIdx.y;
    const int i0 = seg * 28;
    const int t = threadIdx.x, wv = t >> 6, lane = t & 63;
    const size_t colb = (size_t)b * 56;

    for (int e = t; e < 8*32*14; e += 512){           // stage k (float4)
        int g = e / 448, rem = e - g*448, c = rem / 14, jq = rem - c*14;
        float4 f = *(const float4*)(QK + (size_t)(256 + g*32 + c)*NCOL + colb + jq*4);
        *(float4*)&k_s[g][c][jq*4] = f;
    }
    for (int e = t; e < 8*32*7; e += 512){            // stage q (float4)
        int g = e / 224, rem = e - g*224, c = rem / 7, rq = rem - c*7;
        float4 f = *(const float4*)(QK + (size_t)(g*32 + c)*NCOL + colb + i0 + rq*4);
        *(float4*)&q_s[g][c][rq*4] = f;
    }
    __syncthreads();

    const int jj = (lane < 56) ? lane : 55;
    for (int r = wv; r < 28; r += 8){
        const int i = i0 + r;
        float qe[32], ke[32];
        const float* eb = emb + (size_t)i*56 + jj;
        #pragma unroll
        for (int c = 0; c < 32; c++){
            qe[c] = eb[(size_t)c*3136];
            ke[c] = eb[(size_t)(32 + c)*3136];
        }
        for (int g = 0; g < 8; g++){
            const float* qp = &q_s[g][0][r];
            const float* kp = &k_s[g][0][jj];
            float qk = 0.f, qr = 0.f, kr = 0.f;
            #pragma unroll
            for (int c = 0; c < 32; c++){
                float qv = qp[c*28], kv = kp[c*56];
                qk = fmaf(qv, kv, qk);
                qr = fmaf(qv, qe[c], qr);
                kr = fmaf(kv, ke[c], kr);
            }
            float s0 = sgm[g]   *rsqrtf(svr[g]   +EPSBN), h0 = sbt[g]   -smn[g]   *s0;
            float s1 = sgm[8+g] *rsqrtf(svr[8+g] +EPSBN), h1 = sbt[8+g] -smn[8+g] *s1;
            float s2 = sgm[16+g]*rsqrtf(svr[16+g]+EPSBN), h2 = sbt[16+g]-smn[16+g]*s2;
            float val = (lane < 56) ? (fmaf(qk,s0,h0) + fmaf(qr,s1,h1) + fmaf(kr,s2,h2)) : -1e30f;
            float mx = val;
            #pragma unroll
            for (int o = 32; o; o >>= 1) mx = fmaxf(mx, __shfl_xor(mx, o));
            float ex = (lane < 56) ? __expf(val - mx) : 0.f;
            float sum = ex;
            #pragma unroll
            for (int o = 32; o; o >>= 1) sum += __shfl_xor(sum, o);
            if (lane < 56) ats[g][r][lane] = ex / sum;
        }
    }
    __syncthreads();

    for (int e = t; e < 8*64*7; e += 512){            // stage v (uint4 = 8 bf16) over k_s
        int g = e / 448, rem = e - g*448, c = rem / 7, jq = rem - c*7;
        uint4 u = *(const uint4*)(V + (size_t)(g*64 + c)*NCOL + colb + jq*8);
        *(uint4*)&v_s[g][c][jq*8] = u;
    }
    __syncthreads();

    for (int e = t; e < 64*28; e += 512){
        int c = e / 28, r = e - c*28;
        const int i = i0 + r;
        float acc[8] = {0.f,0.f,0.f,0.f,0.f,0.f,0.f,0.f};
        const float* vep = emb + (size_t)(64 + c)*3136 + (size_t)i*56;
        for (int jp = 0; jp < 28; jp++){
            float2 ve2 = *(const float2*)(vep + jp*2);
            #pragma unroll
            for (int g = 0; g < 8; g++){
                float2 a2 = *(const float2*)&ats[g][r][jp*2];
                unsigned u = *(const unsigned*)&v_s[g][c][jp*2];
                float v0 = bf2f(u & 0xffffu);
                float v1 = bf2f(u >> 16);
                acc[g] = fmaf(a2.x, v0 + ve2.x, acc[g]);
                acc[g] = fmaf(a2.y, v1 + ve2.y, acc[g]);
            }
        }
        #pragma unroll
        for (int g = 0; g < 8; g++){
            int oc = g*64 + c;
            float s  = ogm[oc]*rsqrtf(ovr[oc]+EPSBN);
            float hh = obt[oc] - omn[oc]*s;
            y_ws[((size_t)b*512 + oc)*56 + i] = __float2bfloat16(fmaf(acc[g], s, hh));
        }
    }
}

// ---------------------------------------------------------------------------
// y_ws[(n*56+w)][oc][h] (bf16) -> out[n][oc][h][w] (fp32)
// ---------------------------------------------------------------------------
__global__ __launch_bounds__(256) void yT_k(const __hip_bfloat16* __restrict__ y_ws,
                                            float* __restrict__ out){
    __shared__ float tile[56*57];
    const int oc = blockIdx.x, n = blockIdx.y, t = threadIdx.x;
    for (int e = t; e < 56*28; e += 256){
        int w = e / 28, hp = e - w*28;
        unsigned u = *(const unsigned*)(y_ws + ((size_t)(n*56 + w)*512 + oc)*56 + hp*2);
        tile[w*57 + hp*2]     = bf2f(u & 0xffffu);
        tile[w*57 + hp*2 + 1] = bf2f(u >> 16);
    }
    __syncthreads();
    const size_t ob = ((size_t)n*512 + oc)*3136;
    for (int e = t; e < 3136; e += 256){
        int h = e / 56, w = e - h*56;
        out[ob + (size_t)h*56 + w] = tile[w*57 + h];
    }
}

// ---------------------------------------------------------------------------
extern "C" void kernel_launch(void* const* d_in, const int* in_sizes, int n_in,
                              void* d_out, int out_size, void* d_ws, size_t ws_size,
                              hipStream_t stream)
{
    const float* x     = (const float*)d_in[0];
    const float* w_qkv = (const float*)d_in[1];
    const float* qg    = (const float*)d_in[2];
    const float* qb    = (const float*)d_in[3];
    const float* qm    = (const float*)d_in[4];
    const float* qvv   = (const float*)d_in[5];
    const float* rel   = (const float*)d_in[6];
    const float* sg    = (const float*)d_in[7];
    const float* sb    = (const float*)d_in[8];
    const float* sm    = (const float*)d_in[9];
    const float* sv    = (const float*)d_in[10];
    const float* og    = (const float*)d_in[11];
    const float* ob    = (const float*)d_in[12];
    const float* om    = (const float*)d_in[13];
    const float* ov    = (const float*)d_in[14];
    float* out = (float*)d_out;

    char* ws = (char*)d_ws;
    // layout (bytes):
    //   0          emb  f32   1,605,632
    //   1,605,632  w_h  f16   1,048,576
    //   2,654,208  w_l  f16   1,048,576
    //   3,702,784  xt_h f16  51,380,224   (y_ws bf16 overlays after GEMM)
    //  55,083,008  xt_l f16  51,380,224
    // 106,463,232  QK   f32 102,760,448
    // 209,223,680  V   bf16  51,380,224   -> total 260,603,904
    float*          emb  = (float*)ws;
    _Float16*       w_h  = (_Float16*)(ws + 1605632);
    _Float16*       w_l  = (_Float16*)(ws + 2654208);
    _Float16*       xt_h = (_Float16*)(ws + 3702784);
    _Float16*       xt_l = (_Float16*)(ws + 55083008);
    float*          QK   = (float*)(ws + 106463232);
    __hip_bfloat16* Vb   = (__hip_bfloat16*)(ws + 209223680);
    __hip_bfloat16* y_ws = (__hip_bfloat16*)(ws + 3702784);   // over xt_h (dead)
    if (ws_size < 260603904ull) return;

    convw_k<<<dim3(512),      dim3(256), 0, stream>>>(w_qkv, w_h, w_l);
    embg_k <<<dim3(1568),     dim3(256), 0, stream>>>(rel, emb);
    xpose_k<<<dim3(32,56,16), dim3(256), 0, stream>>>(x, xt_h, xt_l);
    gemm_k<true> <<<dim3(4,392), dim3(256), 0, stream>>>(w_h, w_l, xt_h, xt_l, QK, nullptr, qg,qb,qm,qvv);
    gemm_k<false><<<dim3(4,392), dim3(256), 0, stream>>>(w_h, nullptr, xt_h, nullptr, nullptr, Vb, qg,qb,qm,qvv);
    attn3_k<<<dim3(2,896), dim3(512), 0, stream>>>(QK, Vb, emb, sg,sb,sm,sv, og,ob,om,ov, y_ws);
    yT_k   <<<dim3(512,16), dim3(256), 0, stream>>>(y_ws, out);
    (void)in_sizes; (void)n_in; (void)out_size;
}